// Round 10
// baseline (283.851 us; speedup 1.0000x reference)
//
#include <hip/hip_runtime.h>
#include <stdint.h>

// Pipeline (4 dispatches):
//   k_scores: coalesced LDS-staged max-logit+argmax -> unique key + per-block
//             survivor mask (static N(0,1) threshold; no global atomics).
//   k_rank:   36 blocks; rebuild compact survivor list in LDS from masks
//             (popcount + shuffle prefix scan + key gathers), rank own slice by
//             counting (16-batched LDS reads). Exact radix fallback inlined
//             (never taken for N(0,1)). Block 0 zeroes kwinit.
//   k_post:   decode + per-element rank-merge; outputs, order[rank], rank-ordered
//             f64 boxes (class offset folded), kwinit (atomicOr). Zeroes ticket.
//   k_iou:    divide-free f64 suppression bitmask + FUSED sparse greedy scan:
//             last block (device-scope acq_rel ticket) runs the single-wave scan.
//
// Workspace (bytes), ~1.33 MB:
//   keys   [86016]u64 @ 0          (live: k_scores..k_rank)
//   sup    [3008x47]u64 @ 0        (live: k_iou; overlays dead keys)
//   smask  [1344]u64 @ 1131008
//   topk   [3000]u64 @ 1141760
//   order  [3000]u32 @ 1165760
//   kwinit [47]u64   @ 1177760
//   ticket [1]u32    @ 1178144
//   rbox   [3008x4]f64 @ 1178176   (32B aligned)
//   diag   [3008]u64 @ 1274432
//   rowfut [3008]u64 @ 1298496

#define N_ALL 3000
#define N_PAD 3008
#define N_WORDS 47
#define CAP 6144

typedef unsigned long long u64;
typedef uint32_t u32;

// Static 16-bit key-prefix thresholds (prefix = top16 of f32_ord(max_logit)).
// 0xC056 -> logit>=3.34375 (E~2170 of 65536); 0xC03C -> >=2.9375 (E~2180 of 16384);
// 0xC021 -> >=2.515625 (E~1950 of 4096). >=20 sigma inside [1000, CAP] for N(0,1);
// k_rank's inlined exact fallback covers any other distribution.
__device__ __constant__ u32 T16C[3] = {0xC056u, 0xC03Cu, 0xC021u};

__device__ __forceinline__ u32 f32_ord(float x) {
    u32 u = __float_as_uint(x);
    return (u & 0x80000000u) ? ~u : (u | 0x80000000u);
}
__device__ __forceinline__ float ord_f32(u32 o) {
    u32 u = (o & 0x80000000u) ? (o & 0x7FFFFFFFu) : ~o;
    return __uint_as_float(u);
}
__device__ __forceinline__ u64 shfl_u64(u64 v, int src) {
    int lo = __shfl((int)(u32)(v & 0xFFFFFFFFull), src);
    int hi = __shfl((int)(u32)(v >> 32), src);
    return ((u64)(u32)hi << 32) | (u32)(unsigned)lo;
}

// ---------------- K1: max-logit + argmax -> key + per-block survivor mask
__global__ __launch_bounds__(256) void k_scores(
        const float* __restrict__ cls0, const float* __restrict__ cls1,
        const float* __restrict__ cls2, u64* __restrict__ keys,
        u64* __restrict__ smask) {
    __shared__ __align__(16) float tile[64 * 80];   // 20 KB
    __shared__ u64 lds_mask;
    int b = blockIdx.x;
    int lvl, local0, off;
    const float* base;
    if (b < 1024)      { lvl = 0; local0 = b * 64;          base = cls0; off = 0; }
    else if (b < 1280) { lvl = 1; local0 = (b - 1024) * 64; base = cls1; off = 65536; }
    else               { lvl = 2; local0 = (b - 1280) * 64; base = cls2; off = 81920; }
    const float4* src = (const float4*)(base + (size_t)local0 * 80);
    float4* dst = (float4*)tile;
    int tid = threadIdx.x;
    if (tid == 0) lds_mask = 0ull;
#pragma unroll
    for (int k = 0; k < 5; k++) dst[tid + k * 256] = src[tid + k * 256];
    __syncthreads();
    int a = tid >> 2, s = tid & 3;
    const float4* row = (const float4*)(tile + a * 80 + s * 20);
    float m = -3.4e38f; int lab = 0;
#pragma unroll
    for (int q = 0; q < 5; q++) {
        float4 v = row[q];
        int j0 = s * 20 + q * 4;
        if (v.x > m) { m = v.x; lab = j0;     }   // strict > keeps FIRST max (jax argmax)
        if (v.y > m) { m = v.y; lab = j0 + 1; }
        if (v.z > m) { m = v.z; lab = j0 + 2; }
        if (v.w > m) { m = v.w; lab = j0 + 3; }
    }
    float om = __shfl_xor(m, 1); int ol = __shfl_xor(lab, 1);
    if (om > m || (om == m && ol < lab)) { m = om; lab = ol; }
    om = __shfl_xor(m, 2); ol = __shfl_xor(lab, 2);
    if (om > m || (om == m && ol < lab)) { m = om; lab = ol; }
    if (s == 0) {
        int local = local0 + a;
        u64 key = ((u64)f32_ord(m) << 32)
                | ((u64)(0x1FFFFu - (u32)local) << 7)
                | (u64)lab;
        keys[off + local] = key;                   // full key array (fallback path)
        if ((u32)(key >> 48) >= T16C[lvl])         // static threshold survivor
            atomicOr(&lds_mask, 1ull << a);
    }
    __syncthreads();
    if (tid == 0) smask[b] = lds_mask;
}

// ---------------- K2: mask-compact in LDS + rank-by-count -> sorted top-1000.
__global__ __launch_bounds__(256) void k_rank(
        const u64* __restrict__ keys, const u64* __restrict__ smask,
        u64* __restrict__ topk, u64* __restrict__ kwinit) {
    __shared__ u64 buf[CAP];                 // 48 KB
    __shared__ u32 s_hist[256];
    __shared__ u32 swt[4];
    __shared__ u32 s_kk, s_c;
    __shared__ u64 s_pref;
    int lvl = blockIdx.x / 12, sub = blockIdx.x % 12;
    int M, koff, mb, NB, per;
    if (lvl == 0)      { M = 65536; koff = 0;     mb = 0;    NB = 1024; per = 4; }
    else if (lvl == 1) { M = 16384; koff = 65536; mb = 1024; NB = 256;  per = 1; }
    else               { M = 4096;  koff = 81920; mb = 1280; NB = 64;   per = 1; }
    int tid = threadIdx.x, lane = tid & 63, wv = tid >> 6;
    if (blockIdx.x == 0 && tid < N_WORDS) kwinit[tid] = 0ull;   // before k_post
    // load this thread's contiguous mask chunk, count survivors
    u64 mk[4]; u32 mycnt = 0;
#pragma unroll
    for (int p = 0; p < 4; p++) {
        int idx = tid * per + p;
        mk[p] = (p < per && idx < NB) ? smask[mb + idx] : 0ull;
        mycnt += (u32)__popcll(mk[p]);
    }
    // wave inclusive scan + cross-wave prefix
    u32 inc = mycnt;
#pragma unroll
    for (int d = 1; d < 64; d <<= 1) {
        u32 u = __shfl_up(inc, d);
        if (lane >= d) inc += u;
    }
    if (lane == 63) swt[wv] = inc;
    __syncthreads();
    u32 wpre = 0;
    for (int w = 0; w < 4; w++) if (w < wv) wpre += swt[w];
    u32 C = swt[0] + swt[1] + swt[2] + swt[3];
    u32 off = wpre + inc - mycnt;                   // exclusive prefix
    if (C >= 1000u && C <= (u32)CAP) {
        // gather surviving keys into buf (anchor order)
#pragma unroll
        for (int p = 0; p < 4; p++) {
            if (p >= per) break;
            int idx = tid * per + p;
            if (idx < NB) {
                u64 mm = mk[p];
                int abase = idx * 64;
                while (mm) {
                    int bb = __ffsll((long long)mm) - 1;
                    mm &= mm - 1;
                    buf[off++] = keys[koff + abase + bb];
                }
            }
        }
        __syncthreads();
        for (int i = sub * 256 + tid; i < (int)C; i += 3072) {
            u64 x = buf[i];
            int rank = 0;
            int Cr = (int)C & ~15;
            int j = 0;
            for (; j < Cr; j += 16) {        // 16 independent ds_read_b64 per group
                u64 a[16];
#pragma unroll
                for (int q = 0; q < 16; q++) a[q] = buf[j + q];
#pragma unroll
                for (int q = 0; q < 16; q++) rank += (a[q] > x) ? 1 : 0;
            }
            for (; j < (int)C; j++) rank += (buf[j] > x) ? 1 : 0;
            if (rank < 1000) topk[lvl * 1000 + rank] = x;
        }
        return;
    }
    // ---- exact radix fallback (never taken for N(0,1) inputs) ----
    if (sub != 0) return;
    const u64* k = keys + koff;
    if (tid == 0) { s_pref = 0; s_kk = 1000u; s_c = 0; }
    for (int d = 7; d >= 0; d--) {
        if (tid < 256) s_hist[tid] = 0;
        __syncthreads();
        u64 pref = s_pref;
        for (int i = tid; i < M; i += 256) {
            u64 key = k[i];
            if (d == 7 || (key >> ((d + 1) * 8)) == pref)
                atomicAdd(&s_hist[(u32)(key >> (d * 8)) & 255u], 1u);
        }
        __syncthreads();
        if (tid == 0) {
            u32 kk = s_kk, cum = 0;
            for (int b = 255; b >= 0; b--) {
                u32 h = s_hist[b];
                if (cum + h >= kk) { s_pref = (pref << 8) | (u32)b; s_kk = kk - cum; break; }
                cum += h;
            }
        }
        __syncthreads();
    }
    u64 T = s_pref;                             // exact 1000th-largest key
    for (int i = tid; i < M; i += 256) {
        u64 key = k[i];
        if (key >= T) { u32 p = atomicAdd(&s_c, 1u); if (p < 1024u) buf[p] = key; }
    }
    __syncthreads();
    for (int i = tid; i < 1000; i += 256) {
        u64 x = buf[i]; int rank = 0;
        for (int j = 0; j < 1000; j++) rank += (buf[j] > x) ? 1 : 0;
        topk[lvl * 1000 + rank] = x;
    }
}

// ---------------- K3: fused decode + per-element global rank (LDS binary merge).
__device__ __forceinline__ int cnt_desc_lds(const u64* list, u64 x, bool strict) {
    int lo = 0, hi = 1000;
    while (lo < hi) {
        int mid = (lo + hi) >> 1;
        u64 v = list[mid];
        bool in = strict ? (v > x) : (v >= x);
        if (in) lo = mid + 1; else hi = mid;
    }
    return lo;
}
__global__ __launch_bounds__(256) void k_post(
        const u64* __restrict__ topk,
        const float* __restrict__ reg0, const float* __restrict__ reg1,
        const float* __restrict__ reg2, const float* __restrict__ scales,
        float* __restrict__ out, double* __restrict__ rbox,
        u32* __restrict__ order, u64* __restrict__ kwinit,
        u32* __restrict__ ticket) {
    __shared__ u64 lt[N_ALL];                // 24 KB: all three sorted lists
    int tid = threadIdx.x;
    if (blockIdx.x == 0 && tid == 0) *ticket = 0u;   // before k_iou's fused scan
    for (int i = tid; i < N_ALL; i += 256) lt[i] = topk[i];
    __syncthreads();
    int r = blockIdx.x * 256 + tid;
    if (r >= N_ALL) return;
    int lvl = r / 1000;
    u64 key = lt[r];
    u32 low = (u32)key;
    int lab = (int)(low & 0x7Fu);
    int local = 0x1FFFF - (int)((low >> 7) & 0x1FFFFu);
    float logit = ord_f32((u32)(key >> 32));
    float score = 1.0f / (1.0f + expf(-logit));
    const float* regp = (lvl == 0 ? reg0 : (lvl == 1 ? reg1 : reg2));
    float4 rg = *(const float4*)(regp + (size_t)local * 4);
    float scale = scales[lvl];
    int wlog = 8 - lvl;                       // grid width 256/128/64
    int x = local & ((1 << wlog) - 1);
    int y = local >> wlog;
    float stridef = (float)(8 << lvl);
    float ax = ((float)x + 0.5f) * stridef;
    float ay = ((float)y + 0.5f) * stridef;
    float sx = 1.0f / (1.0f + expf(-rg.x));
    float sy = 1.0f / (1.0f + expf(-rg.y));
    float cx = ax + (sx * 3.0f - 1.5f);
    float cy = ay + (sy * 3.0f - 1.5f);
    float ww = expf(rg.z * scale);
    float hh = expf(rg.w * scale);
    float b0 = (cx - 0.5f * ww) * stridef;    // reference multiplies by stride AGAIN
    float b1 = (cy - 0.5f * hh) * stridef;
    float b2 = (cx + 0.5f * ww) * stridef;
    float b3 = (cy + 0.5f * hh) * stridef;
    const float inv = 1.0f / 2048.0f;         // exact pow2
    out[r * 4 + 0] = fminf(fmaxf(b0 * inv, 0.0f), 1.0f);
    out[r * 4 + 1] = fminf(fmaxf(b1 * inv, 0.0f), 1.0f);
    out[r * 4 + 2] = fminf(fmaxf(b2 * inv, 0.0f), 1.0f);
    out[r * 4 + 3] = fminf(fmaxf(b3 * inv, 0.0f), 1.0f);
    out[12000 + r] = score;
    out[15000 + r] = (float)lab;
    int rank = r - lvl * 1000;                // merge position among 3 sorted lists
#pragma unroll
    for (int L2 = 0; L2 < 3; L2++)
        if (L2 != lvl) rank += cnt_desc_lds(lt + L2 * 1000, key, L2 > lvl);
    order[rank] = (u32)r;
    double c = (double)lab * 8192.0;          // class offset folded in, f64 exact
    double4 rb;
    rb.x = (double)b0 + c; rb.y = (double)b1 + c;
    rb.z = (double)b2 + c; rb.w = (double)b3 + c;
    ((double4*)rbox)[rank] = rb;
    if (score >= 0.05f) atomicOr(&kwinit[rank >> 6], 1ull << (rank & 63));
}

// ---------------- K4: suppression bitmask + fused sparse greedy scan.
// Divide-free: iou > 0.6 <=> inter > 0.6*union. Offsets pre-folded in rbox.
// Last block (agent-scope acq_rel ticket) runs the single-wave scan inline.
__global__ __launch_bounds__(256) void k_iou(
        const double* __restrict__ rbox, u64* __restrict__ sup,
        u64* __restrict__ diag, u64* __restrict__ rowfut,
        const u64* __restrict__ kwinit, const u32* __restrict__ order,
        u32* __restrict__ ticket, float* __restrict__ out_keep) {
    int s = blockIdx.x;
    int tid = threadIdx.x;
    __shared__ u64 s_rf;
    __shared__ int s_last;
    if (tid == 0) s_rf = 0;
    __syncthreads();
    int tword = s >> 6;
    bool srow_ok = (s < N_ALL);
    const double4* rb4 = (const double4*)rbox;
    double ix1 = 0, iy1 = 0, ix2 = 0, iy2 = 0, iarea = 0;
    if (srow_ok) {
        double4 b = rb4[s];
        ix1 = b.x; iy1 = b.y; ix2 = b.z; iy2 = b.w;
        iarea = (ix2 - ix1) * (iy2 - iy1);
    }
    for (int j = (tword << 6) + tid; j < N_PAD; j += 256) {
        bool sb = false;
        if (srow_ok && j < N_ALL && j > s) {
            double4 bj = rb4[j];
            double xx1 = fmax(ix1, bj.x), yy1 = fmax(iy1, bj.y);
            double xx2 = fmin(ix2, bj.z), yy2 = fmin(iy2, bj.w);
            double w = fmax(1e-10, xx2 - xx1);
            double h = fmax(1e-10, yy2 - yy1);
            double inter = w * h;
            double jarea = (bj.z - bj.x) * (bj.w - bj.y);
            double uni = iarea + jarea - inter + 1e-14;
            sb = inter > 0.6 * uni;
        }
        u64 bal = __ballot(sb);
        if ((j & 63) == 0) {
            int w = j >> 6;
            sup[(size_t)s * N_WORDS + w] = bal;
            if (w == tword) diag[s] = bal;
            if (w > tword && bal) atomicOr(&s_rf, 1ull << w);
        }
    }
    __syncthreads();
    if (tid == 0) {
        rowfut[s] = s_rf;
        __threadfence();                            // release this block's sup/diag/rowfut
        u32 t = __hip_atomic_fetch_add(ticket, 1u, __ATOMIC_ACQ_REL,
                                       __HIP_MEMORY_SCOPE_AGENT);
        s_last = (t == (u32)(N_PAD - 1)) ? 1 : 0;   // all 3008 blocks done
    }
    __syncthreads();
    if (!s_last || tid >= 64) return;
    // ---- fused sparse sequential greedy scan (wave 0 of the last block) ----
    int lane = tid;
    u64 kw = (lane < N_WORDS) ? kwinit[lane] : 0ull;   // lane holds keep-word `lane`
    u64 d  = diag[lane];                               // tile 0 prefetch
    u64 rf = rowfut[lane];
    for (int t = 0; t < N_WORDS; t++) {
        u64 dn = 0, rfn = 0;
        if (t < N_WORDS - 1) {                         // prefetch next tile
            dn  = diag[(t + 1) * 64 + lane];
            rfn = rowfut[(t + 1) * 64 + lane];
        }
        u64 km = shfl_u64(kw, t);                      // keep word of this tile (uniform)
        u64 nzd = __ballot(d != 0ull);
        u64 todo = nzd;
        while (true) {                                 // uniform loop, usually 0-3 iters
            u64 c = todo & km;
            if (!c) break;
            int b = __ffsll((long long)c) - 1;
            todo &= ~(1ull << b);
            u64 m = shfl_u64(d, b);
            km &= ~m;
        }
        if (lane == t) kw = km;
        u64 appl = km & __ballot(rf != 0ull);          // kept rows with future bits
        while (appl) {                                 // usually 0 iters
            int b = __ffsll((long long)appl) - 1;
            appl &= appl - 1;
            u64 rfb = shfl_u64(rf, b);
            u64 m2 = 0ull;
            if (lane < N_WORDS && ((rfb >> lane) & 1ull))
                m2 = sup[(size_t)(t * 64 + b) * N_WORDS + lane];
            kw &= ~m2;                                 // rfb bits are all > t
        }
        d = dn; rf = rfn;
    }
    if (lane < N_WORDS) {
#pragma unroll 16
        for (int b = 0; b < 64; b++) {
            int j = lane * 64 + b;
            if (j < N_ALL) out_keep[order[j]] = ((kw >> b) & 1ull) ? 1.0f : 0.0f;
        }
    }
}

extern "C" void kernel_launch(void* const* d_in, const int* in_sizes, int n_in,
                              void* d_out, int out_size, void* d_ws, size_t ws_size,
                              hipStream_t stream) {
    const float* cls0   = (const float*)d_in[0];
    const float* reg0   = (const float*)d_in[1];
    const float* cls1   = (const float*)d_in[2];
    const float* reg1   = (const float*)d_in[3];
    const float* cls2   = (const float*)d_in[4];
    const float* reg2   = (const float*)d_in[5];
    const float* scales = (const float*)d_in[6];
    float* out = (float*)d_out;
    char* ws = (char*)d_ws;
    u64* keys   = (u64*)(ws + 0);            // dead after k_rank
    u64* sup    = (u64*)(ws + 0);            // written by k_iou (after keys die)
    u64* smask  = (u64*)(ws + 1131008);
    u64* topk   = (u64*)(ws + 1141760);
    u32* order  = (u32*)(ws + 1165760);
    u64* kwinit = (u64*)(ws + 1177760);
    u32* ticket = (u32*)(ws + 1178144);
    double* rbox= (double*)(ws + 1178176);   // 32B aligned
    u64* diag   = (u64*)(ws + 1274432);
    u64* rowfut = (u64*)(ws + 1298496);

    k_scores<<<1344, 256, 0, stream>>>(cls0, cls1, cls2, keys, smask);
    k_rank<<<36, 256, 0, stream>>>(keys, smask, topk, kwinit);
    k_post<<<12, 256, 0, stream>>>(topk, reg0, reg1, reg2, scales, out, rbox, order, kwinit, ticket);
    k_iou<<<N_PAD, 256, 0, stream>>>(rbox, sup, diag, rowfut, kwinit, order, ticket, out + 18000);
}

// Round 11
// 173.387 us; speedup vs baseline: 1.6371x; 1.6371x over previous
//
#include <hip/hip_runtime.h>
#include <stdint.h>

// Pipeline (5 dispatches):
//   k_scores: coalesced LDS-staged max-logit+argmax -> unique key + per-block
//             survivor mask (static N(0,1) threshold; no global atomics).
//   k_rank:   36 blocks; rebuild compact survivor list in LDS from masks
//             (popcount + shuffle prefix scan + key gathers), rank own slice by
//             counting (16-batched LDS reads). Exact radix fallback inlined
//             (never taken for N(0,1)). Block 0 zeroes kwinit.
//   k_post:   decode + per-element rank-merge; outputs, order[rank], rank-ordered
//             f64 boxes (class offset folded), kwinit (atomicOr).
//   k_iou:    divide-free f64 suppression bitmask, coalesced double4 reads.
//   k_scan:   sparse sequential greedy scan, single wave.
// NOTE (R10 lesson): do NOT fuse k_iou+k_scan via ticket — 3008 per-block
// device fences serialize at ~38ns each (+115us). Tickets only for small grids.
//
// Workspace (bytes), ~1.33 MB:
//   keys   [86016]u64 @ 0          (live: k_scores..k_rank)
//   sup    [3008x47]u64 @ 0        (live: k_iou..k_scan; overlays dead keys)
//   smask  [1344]u64 @ 1131008
//   topk   [3000]u64 @ 1141760
//   order  [3000]u32 @ 1165760
//   kwinit [47]u64   @ 1177760
//   rbox   [3008x4]f64 @ 1178176   (32B aligned)
//   diag   [3008]u64 @ 1274432
//   rowfut [3008]u64 @ 1298496

#define N_ALL 3000
#define N_PAD 3008
#define N_WORDS 47
#define CAP 6144

typedef unsigned long long u64;
typedef uint32_t u32;

// Static 16-bit key-prefix thresholds (prefix = top16 of f32_ord(max_logit)).
// 0xC056 -> logit>=3.34375 (E~2170 of 65536); 0xC03C -> >=2.9375 (E~2180 of 16384);
// 0xC021 -> >=2.515625 (E~1950 of 4096). >=20 sigma inside [1000, CAP] for N(0,1);
// k_rank's inlined exact fallback covers any other distribution.
__device__ __constant__ u32 T16C[3] = {0xC056u, 0xC03Cu, 0xC021u};

__device__ __forceinline__ u32 f32_ord(float x) {
    u32 u = __float_as_uint(x);
    return (u & 0x80000000u) ? ~u : (u | 0x80000000u);
}
__device__ __forceinline__ float ord_f32(u32 o) {
    u32 u = (o & 0x80000000u) ? (o & 0x7FFFFFFFu) : ~o;
    return __uint_as_float(u);
}
__device__ __forceinline__ u64 shfl_u64(u64 v, int src) {
    int lo = __shfl((int)(u32)(v & 0xFFFFFFFFull), src);
    int hi = __shfl((int)(u32)(v >> 32), src);
    return ((u64)(u32)hi << 32) | (u32)(unsigned)lo;
}

// ---------------- K1: max-logit + argmax -> key + per-block survivor mask
__global__ __launch_bounds__(256) void k_scores(
        const float* __restrict__ cls0, const float* __restrict__ cls1,
        const float* __restrict__ cls2, u64* __restrict__ keys,
        u64* __restrict__ smask) {
    __shared__ __align__(16) float tile[64 * 80];   // 20 KB
    __shared__ u64 lds_mask;
    int b = blockIdx.x;
    int lvl, local0, off;
    const float* base;
    if (b < 1024)      { lvl = 0; local0 = b * 64;          base = cls0; off = 0; }
    else if (b < 1280) { lvl = 1; local0 = (b - 1024) * 64; base = cls1; off = 65536; }
    else               { lvl = 2; local0 = (b - 1280) * 64; base = cls2; off = 81920; }
    const float4* src = (const float4*)(base + (size_t)local0 * 80);
    float4* dst = (float4*)tile;
    int tid = threadIdx.x;
    if (tid == 0) lds_mask = 0ull;
#pragma unroll
    for (int k = 0; k < 5; k++) dst[tid + k * 256] = src[tid + k * 256];
    __syncthreads();
    int a = tid >> 2, s = tid & 3;
    const float4* row = (const float4*)(tile + a * 80 + s * 20);
    float m = -3.4e38f; int lab = 0;
#pragma unroll
    for (int q = 0; q < 5; q++) {
        float4 v = row[q];
        int j0 = s * 20 + q * 4;
        if (v.x > m) { m = v.x; lab = j0;     }   // strict > keeps FIRST max (jax argmax)
        if (v.y > m) { m = v.y; lab = j0 + 1; }
        if (v.z > m) { m = v.z; lab = j0 + 2; }
        if (v.w > m) { m = v.w; lab = j0 + 3; }
    }
    float om = __shfl_xor(m, 1); int ol = __shfl_xor(lab, 1);
    if (om > m || (om == m && ol < lab)) { m = om; lab = ol; }
    om = __shfl_xor(m, 2); ol = __shfl_xor(lab, 2);
    if (om > m || (om == m && ol < lab)) { m = om; lab = ol; }
    if (s == 0) {
        int local = local0 + a;
        u64 key = ((u64)f32_ord(m) << 32)
                | ((u64)(0x1FFFFu - (u32)local) << 7)
                | (u64)lab;
        keys[off + local] = key;                   // full key array (fallback path)
        if ((u32)(key >> 48) >= T16C[lvl])         // static threshold survivor
            atomicOr(&lds_mask, 1ull << a);
    }
    __syncthreads();
    if (tid == 0) smask[b] = lds_mask;
}

// ---------------- K2: mask-compact in LDS + rank-by-count -> sorted top-1000.
__global__ __launch_bounds__(256) void k_rank(
        const u64* __restrict__ keys, const u64* __restrict__ smask,
        u64* __restrict__ topk, u64* __restrict__ kwinit) {
    __shared__ u64 buf[CAP];                 // 48 KB
    __shared__ u32 s_hist[256];
    __shared__ u32 swt[4];
    __shared__ u32 s_kk, s_c;
    __shared__ u64 s_pref;
    int lvl = blockIdx.x / 12, sub = blockIdx.x % 12;
    int M, koff, mb, NB, per;
    if (lvl == 0)      { M = 65536; koff = 0;     mb = 0;    NB = 1024; per = 4; }
    else if (lvl == 1) { M = 16384; koff = 65536; mb = 1024; NB = 256;  per = 1; }
    else               { M = 4096;  koff = 81920; mb = 1280; NB = 64;   per = 1; }
    int tid = threadIdx.x, lane = tid & 63, wv = tid >> 6;
    if (blockIdx.x == 0 && tid < N_WORDS) kwinit[tid] = 0ull;   // before k_post
    // load this thread's contiguous mask chunk, count survivors
    u64 mk[4]; u32 mycnt = 0;
#pragma unroll
    for (int p = 0; p < 4; p++) {
        int idx = tid * per + p;
        mk[p] = (p < per && idx < NB) ? smask[mb + idx] : 0ull;
        mycnt += (u32)__popcll(mk[p]);
    }
    // wave inclusive scan + cross-wave prefix
    u32 inc = mycnt;
#pragma unroll
    for (int d = 1; d < 64; d <<= 1) {
        u32 u = __shfl_up(inc, d);
        if (lane >= d) inc += u;
    }
    if (lane == 63) swt[wv] = inc;
    __syncthreads();
    u32 wpre = 0;
    for (int w = 0; w < 4; w++) if (w < wv) wpre += swt[w];
    u32 C = swt[0] + swt[1] + swt[2] + swt[3];
    u32 off = wpre + inc - mycnt;                   // exclusive prefix
    if (C >= 1000u && C <= (u32)CAP) {
        // gather surviving keys into buf (anchor order)
#pragma unroll
        for (int p = 0; p < 4; p++) {
            if (p >= per) break;
            int idx = tid * per + p;
            if (idx < NB) {
                u64 mm = mk[p];
                int abase = idx * 64;
                while (mm) {
                    int bb = __ffsll((long long)mm) - 1;
                    mm &= mm - 1;
                    buf[off++] = keys[koff + abase + bb];
                }
            }
        }
        __syncthreads();
        for (int i = sub * 256 + tid; i < (int)C; i += 3072) {
            u64 x = buf[i];
            int rank = 0;
            int Cr = (int)C & ~15;
            int j = 0;
            for (; j < Cr; j += 16) {        // 16 independent ds_read_b64 per group
                u64 a[16];
#pragma unroll
                for (int q = 0; q < 16; q++) a[q] = buf[j + q];
#pragma unroll
                for (int q = 0; q < 16; q++) rank += (a[q] > x) ? 1 : 0;
            }
            for (; j < (int)C; j++) rank += (buf[j] > x) ? 1 : 0;
            if (rank < 1000) topk[lvl * 1000 + rank] = x;
        }
        return;
    }
    // ---- exact radix fallback (never taken for N(0,1) inputs) ----
    if (sub != 0) return;
    const u64* k = keys + koff;
    if (tid == 0) { s_pref = 0; s_kk = 1000u; s_c = 0; }
    for (int d = 7; d >= 0; d--) {
        if (tid < 256) s_hist[tid] = 0;
        __syncthreads();
        u64 pref = s_pref;
        for (int i = tid; i < M; i += 256) {
            u64 key = k[i];
            if (d == 7 || (key >> ((d + 1) * 8)) == pref)
                atomicAdd(&s_hist[(u32)(key >> (d * 8)) & 255u], 1u);
        }
        __syncthreads();
        if (tid == 0) {
            u32 kk = s_kk, cum = 0;
            for (int b = 255; b >= 0; b--) {
                u32 h = s_hist[b];
                if (cum + h >= kk) { s_pref = (pref << 8) | (u32)b; s_kk = kk - cum; break; }
                cum += h;
            }
        }
        __syncthreads();
    }
    u64 T = s_pref;                             // exact 1000th-largest key
    for (int i = tid; i < M; i += 256) {
        u64 key = k[i];
        if (key >= T) { u32 p = atomicAdd(&s_c, 1u); if (p < 1024u) buf[p] = key; }
    }
    __syncthreads();
    for (int i = tid; i < 1000; i += 256) {
        u64 x = buf[i]; int rank = 0;
        for (int j = 0; j < 1000; j++) rank += (buf[j] > x) ? 1 : 0;
        topk[lvl * 1000 + rank] = x;
    }
}

// ---------------- K3: fused decode + per-element global rank (LDS binary merge).
__device__ __forceinline__ int cnt_desc_lds(const u64* list, u64 x, bool strict) {
    int lo = 0, hi = 1000;
    while (lo < hi) {
        int mid = (lo + hi) >> 1;
        u64 v = list[mid];
        bool in = strict ? (v > x) : (v >= x);
        if (in) lo = mid + 1; else hi = mid;
    }
    return lo;
}
__global__ __launch_bounds__(256) void k_post(
        const u64* __restrict__ topk,
        const float* __restrict__ reg0, const float* __restrict__ reg1,
        const float* __restrict__ reg2, const float* __restrict__ scales,
        float* __restrict__ out, double* __restrict__ rbox,
        u32* __restrict__ order, u64* __restrict__ kwinit) {
    __shared__ u64 lt[N_ALL];                // 24 KB: all three sorted lists
    int tid = threadIdx.x;
    for (int i = tid; i < N_ALL; i += 256) lt[i] = topk[i];
    __syncthreads();
    int r = blockIdx.x * 256 + tid;
    if (r >= N_ALL) return;
    int lvl = r / 1000;
    u64 key = lt[r];
    u32 low = (u32)key;
    int lab = (int)(low & 0x7Fu);
    int local = 0x1FFFF - (int)((low >> 7) & 0x1FFFFu);
    float logit = ord_f32((u32)(key >> 32));
    float score = 1.0f / (1.0f + expf(-logit));
    const float* regp = (lvl == 0 ? reg0 : (lvl == 1 ? reg1 : reg2));
    float4 rg = *(const float4*)(regp + (size_t)local * 4);
    float scale = scales[lvl];
    int wlog = 8 - lvl;                       // grid width 256/128/64
    int x = local & ((1 << wlog) - 1);
    int y = local >> wlog;
    float stridef = (float)(8 << lvl);
    float ax = ((float)x + 0.5f) * stridef;
    float ay = ((float)y + 0.5f) * stridef;
    float sx = 1.0f / (1.0f + expf(-rg.x));
    float sy = 1.0f / (1.0f + expf(-rg.y));
    float cx = ax + (sx * 3.0f - 1.5f);
    float cy = ay + (sy * 3.0f - 1.5f);
    float ww = expf(rg.z * scale);
    float hh = expf(rg.w * scale);
    float b0 = (cx - 0.5f * ww) * stridef;    // reference multiplies by stride AGAIN
    float b1 = (cy - 0.5f * hh) * stridef;
    float b2 = (cx + 0.5f * ww) * stridef;
    float b3 = (cy + 0.5f * hh) * stridef;
    const float inv = 1.0f / 2048.0f;         // exact pow2
    out[r * 4 + 0] = fminf(fmaxf(b0 * inv, 0.0f), 1.0f);
    out[r * 4 + 1] = fminf(fmaxf(b1 * inv, 0.0f), 1.0f);
    out[r * 4 + 2] = fminf(fmaxf(b2 * inv, 0.0f), 1.0f);
    out[r * 4 + 3] = fminf(fmaxf(b3 * inv, 0.0f), 1.0f);
    out[12000 + r] = score;
    out[15000 + r] = (float)lab;
    int rank = r - lvl * 1000;                // merge position among 3 sorted lists
#pragma unroll
    for (int L2 = 0; L2 < 3; L2++)
        if (L2 != lvl) rank += cnt_desc_lds(lt + L2 * 1000, key, L2 > lvl);
    order[rank] = (u32)r;
    double c = (double)lab * 8192.0;          // class offset folded in, f64 exact
    double4 rb;
    rb.x = (double)b0 + c; rb.y = (double)b1 + c;
    rb.z = (double)b2 + c; rb.w = (double)b3 + c;
    ((double4*)rbox)[rank] = rb;
    if (score >= 0.05f) atomicOr(&kwinit[rank >> 6], 1ull << (rank & 63));
}

// ---------------- K4: suppression bitmask rows, coalesced double4 reads.
// Divide-free: iou > 0.6 <=> inter > 0.6*union. Offsets pre-folded in rbox.
__global__ __launch_bounds__(256) void k_iou(
        const double* __restrict__ rbox, u64* __restrict__ sup,
        u64* __restrict__ diag, u64* __restrict__ rowfut) {
    int s = blockIdx.x;
    int tid = threadIdx.x;
    __shared__ u64 s_rf;
    if (tid == 0) s_rf = 0;
    __syncthreads();
    int tword = s >> 6;
    bool srow_ok = (s < N_ALL);
    const double4* rb4 = (const double4*)rbox;
    double ix1 = 0, iy1 = 0, ix2 = 0, iy2 = 0, iarea = 0;
    if (srow_ok) {
        double4 b = rb4[s];
        ix1 = b.x; iy1 = b.y; ix2 = b.z; iy2 = b.w;
        iarea = (ix2 - ix1) * (iy2 - iy1);
    }
    for (int j = (tword << 6) + tid; j < N_PAD; j += 256) {
        bool sb = false;
        if (srow_ok && j < N_ALL && j > s) {
            double4 bj = rb4[j];
            double xx1 = fmax(ix1, bj.x), yy1 = fmax(iy1, bj.y);
            double xx2 = fmin(ix2, bj.z), yy2 = fmin(iy2, bj.w);
            double w = fmax(1e-10, xx2 - xx1);
            double h = fmax(1e-10, yy2 - yy1);
            double inter = w * h;
            double jarea = (bj.z - bj.x) * (bj.w - bj.y);
            double uni = iarea + jarea - inter + 1e-14;
            sb = inter > 0.6 * uni;
        }
        u64 bal = __ballot(sb);
        if ((j & 63) == 0) {
            int w = j >> 6;
            sup[(size_t)s * N_WORDS + w] = bal;
            if (w == tword) diag[s] = bal;
            if (w > tword && bal) atomicOr(&s_rf, 1ull << w);
        }
    }
    __syncthreads();
    if (tid == 0) rowfut[s] = s_rf;
}

// ---------------- K5: sparse sequential greedy scan, single wave.
__global__ __launch_bounds__(64) void k_scan(
        const u64* __restrict__ sup, const u64* __restrict__ diag,
        const u64* __restrict__ rowfut, const u64* __restrict__ kwinit,
        const u32* __restrict__ order, float* __restrict__ out_keep) {
    int lane = threadIdx.x;
    u64 kw = (lane < N_WORDS) ? kwinit[lane] : 0ull;   // lane holds keep-word `lane`
    u64 d  = diag[lane];                               // tile 0 prefetch
    u64 rf = rowfut[lane];
    for (int t = 0; t < N_WORDS; t++) {
        u64 dn = 0, rfn = 0;
        if (t < N_WORDS - 1) {                         // prefetch next tile
            dn  = diag[(t + 1) * 64 + lane];
            rfn = rowfut[(t + 1) * 64 + lane];
        }
        u64 km = shfl_u64(kw, t);                      // keep word of this tile (uniform)
        u64 nzd = __ballot(d != 0ull);
        u64 todo = nzd;
        while (true) {                                 // uniform loop, usually 0-3 iters
            u64 c = todo & km;
            if (!c) break;
            int b = __ffsll((long long)c) - 1;
            todo &= ~(1ull << b);
            u64 m = shfl_u64(d, b);
            km &= ~m;
        }
        if (lane == t) kw = km;
        u64 appl = km & __ballot(rf != 0ull);          // kept rows with future bits
        while (appl) {                                 // usually 0 iters
            int b = __ffsll((long long)appl) - 1;
            appl &= appl - 1;
            u64 rfb = shfl_u64(rf, b);
            u64 m2 = 0ull;
            if (lane < N_WORDS && ((rfb >> lane) & 1ull))
                m2 = sup[(size_t)(t * 64 + b) * N_WORDS + lane];
            kw &= ~m2;                                 // rfb bits are all > t
        }
        d = dn; rf = rfn;
    }
    if (lane < N_WORDS) {
#pragma unroll 16
        for (int b = 0; b < 64; b++) {
            int j = lane * 64 + b;
            if (j < N_ALL) out_keep[order[j]] = ((kw >> b) & 1ull) ? 1.0f : 0.0f;
        }
    }
}

extern "C" void kernel_launch(void* const* d_in, const int* in_sizes, int n_in,
                              void* d_out, int out_size, void* d_ws, size_t ws_size,
                              hipStream_t stream) {
    const float* cls0   = (const float*)d_in[0];
    const float* reg0   = (const float*)d_in[1];
    const float* cls1   = (const float*)d_in[2];
    const float* reg1   = (const float*)d_in[3];
    const float* cls2   = (const float*)d_in[4];
    const float* reg2   = (const float*)d_in[5];
    const float* scales = (const float*)d_in[6];
    float* out = (float*)d_out;
    char* ws = (char*)d_ws;
    u64* keys   = (u64*)(ws + 0);            // dead after k_rank
    u64* sup    = (u64*)(ws + 0);            // written by k_iou (after keys die)
    u64* smask  = (u64*)(ws + 1131008);
    u64* topk   = (u64*)(ws + 1141760);
    u32* order  = (u32*)(ws + 1165760);
    u64* kwinit = (u64*)(ws + 1177760);
    double* rbox= (double*)(ws + 1178176);   // 32B aligned
    u64* diag   = (u64*)(ws + 1274432);
    u64* rowfut = (u64*)(ws + 1298496);

    k_scores<<<1344, 256, 0, stream>>>(cls0, cls1, cls2, keys, smask);
    k_rank<<<36, 256, 0, stream>>>(keys, smask, topk, kwinit);
    k_post<<<12, 256, 0, stream>>>(topk, reg0, reg1, reg2, scales, out, rbox, order, kwinit);
    k_iou<<<N_PAD, 256, 0, stream>>>(rbox, sup, diag, rowfut);
    k_scan<<<1, 64, 0, stream>>>(sup, diag, rowfut, kwinit, order, out + 18000);
}